// Round 11
// baseline (16204.259 us; speedup 1.0000x reference)
//
#include <hip/hip_runtime.h>
#include <hip/hip_bf16.h>
#include <stdint.h>

// RNN: h_t = relu(xs_t @ W_ih^T + h_{t-1} @ W_hh^T); ys = (h_seq @ W_out^T) -> [B,T,O]
// R11: XCD-local exchange via parity-tagged ring (fixes R10's lossy P' encoding).
//  - hseq (128MiB): P from phase 1 (LOSSLESS), block-private in recurrence (writer wave
//    reads P_t, overwrites h_t in place for phase 3). Plain cacheable ops only.
//  - Exchange: 4-slot ring (1MiB, L2-hot). Producer plain-stores h tagged with parity
//    (all bf16 signs = 1-((t>>2)&1); h>=0 -> signs free, lossless). Slot reuse period 4
//    vs provable skew <=1 => stale always has opposite parity: deterministic rejection.
//    memset-0 ring: signs clear != tag(0)=1 -> startup safe. 16B granule = check granule.
//  - Consumer: <=8 sc0 retries (L2-served, same-XCD fast path under default round-robin
//    bid&7=XCD) then sc0sc1 LLC-mirror loop (correct under ANY placement, G16).
//  - No flags, no fences, no drains anywhere.

#define TT 512
#define BB 64
#define NIN 1024
#define NH 2048
#define NOUT 1024

typedef __attribute__((ext_vector_type(8))) short bf8;
typedef __attribute__((ext_vector_type(4))) float f4;
typedef __attribute__((ext_vector_type(4))) unsigned int u4;

static __device__ __forceinline__ unsigned short f2bf(float f) {
  __hip_bfloat16 h = __float2bfloat16(f);
  return __builtin_bit_cast(unsigned short, h);
}
static __device__ __forceinline__ float bf2f(unsigned short v) {
  return __bfloat162float(__builtin_bit_cast(__hip_bfloat16, v));
}
static __device__ __forceinline__ u4 pack8(const float* f) {
  u4 r;
#pragma unroll
  for (int i = 0; i < 4; ++i) {
    unsigned lo = f2bf(f[2 * i]);
    unsigned hi = f2bf(f[2 * i + 1]);
    r[i] = lo | (hi << 16);
  }
  return r;
}

// slice layout: (m = t*64+b, col) -> [t][g=b>>3][jb=col>>6][r=b&7][jl=col&63]
static __device__ __forceinline__ size_t sl_idx8(int m, int col) {
  return ((((size_t)(m >> 6) * 8 + ((m & 63) >> 3)) * 32 + (col >> 6)) << 9) +
         (size_t)((m & 63) & 7) * 64 + (col & 63);
}

// ---------------- generic C[M,N] = A[M,K] * B[N,K]^T (bf16 MFMA) ----------------
// <false,false>: phase 1 (A=f32 xs, store plain bf16 P into sliced layout).
// <true,true>:   phase 3 (A=h in sliced layout, strip tag signs; store f32 [B,T,O]).
template <bool ABF, bool TRANS>
__global__ void gemm_bt(const void* __restrict__ Av, const float* __restrict__ Bw,
                        void* __restrict__ Cv, int M, int N, int K) {
  constexpr int BM = 128, BN = 128, BK = 32;
  __shared__ u4 As[BM * 4];
  __shared__ u4 Bs[BN * 4];
  const int nt = N / BN;
  const int mi = (int)blockIdx.x / nt;
  const int ni = (int)blockIdx.x % nt;
  const int m0 = mi * BM, n0 = ni * BN;
  const int t = threadIdx.x;
  const int l = t & 63, w = t >> 6, wr = w >> 1, wc = w & 1;
  const int lr = l & 15, lq = l >> 4;

  f4 acc[4][4] = {};

  const int srow = t >> 1;
  const int sc0 = (t & 1) * 2;
  const u4 msk = {0x7fff7fffu, 0x7fff7fffu, 0x7fff7fffu, 0x7fff7fffu};

  for (int kt = 0; kt < K; kt += BK) {
    if (ABF) {
      const unsigned short* A = (const unsigned short*)Av;
#pragma unroll
      for (int cc = 0; cc < 2; ++cc) {
        int c = sc0 + cc;
        u4 v = *(const u4*)(A + sl_idx8(m0 + srow, kt + c * 8));
        v &= msk;  // strip tag sign bits (h may carry parity tag)
        As[srow * 4 + (c ^ ((srow ^ (srow >> 2)) & 3))] = v;
      }
    } else {
      const float* A = (const float*)Av;
#pragma unroll
      for (int cc = 0; cc < 2; ++cc) {
        int c = sc0 + cc;
        const float* p = A + (size_t)(m0 + srow) * K + kt + c * 8;
        float4 v0 = *(const float4*)p;
        float4 v1 = *(const float4*)(p + 4);
        float f[8] = {v0.x, v0.y, v0.z, v0.w, v1.x, v1.y, v1.z, v1.w};
        As[srow * 4 + (c ^ ((srow ^ (srow >> 2)) & 3))] = pack8(f);
      }
    }
#pragma unroll
    for (int cc = 0; cc < 2; ++cc) {
      int c = sc0 + cc;
      const float* p = Bw + (size_t)(n0 + srow) * K + kt + c * 8;
      float4 v0 = *(const float4*)p;
      float4 v1 = *(const float4*)(p + 4);
      float f[8] = {v0.x, v0.y, v0.z, v0.w, v1.x, v1.y, v1.z, v1.w};
      Bs[srow * 4 + (c ^ ((srow ^ (srow >> 2)) & 3))] = pack8(f);
    }
    __syncthreads();

    bf8 a[4], b[4];
#pragma unroll
    for (int i = 0; i < 4; ++i) {
      int ra = wr * 64 + i * 16 + lr;
      a[i] = __builtin_bit_cast(bf8, As[ra * 4 + (lq ^ ((ra ^ (ra >> 2)) & 3))]);
      int rb = wc * 64 + i * 16 + lr;
      b[i] = __builtin_bit_cast(bf8, Bs[rb * 4 + (lq ^ ((rb ^ (rb >> 2)) & 3))]);
    }
#pragma unroll
    for (int i = 0; i < 4; ++i)
#pragma unroll
      for (int j = 0; j < 4; ++j)
        acc[i][j] = __builtin_amdgcn_mfma_f32_16x16x32_bf16(a[i], b[j], acc[i][j], 0, 0, 0);
    __syncthreads();
  }

  if (TRANS) {
    float* C = (float*)Cv;
#pragma unroll
    for (int i = 0; i < 4; ++i)
#pragma unroll
      for (int j = 0; j < 4; ++j)
#pragma unroll
        for (int r = 0; r < 4; ++r) {
          int m = m0 + wr * 64 + i * 16 + lq * 4 + r;
          int n = n0 + wc * 64 + j * 16 + lr;
          C[(size_t)(m & 63) * (TT * NOUT) + (size_t)(m >> 6) * NOUT + n] = acc[i][j][r];
        }
  } else {
    unsigned short* C = (unsigned short*)Cv;
#pragma unroll
    for (int i = 0; i < 4; ++i)
#pragma unroll
      for (int j = 0; j < 4; ++j)
#pragma unroll
        for (int r = 0; r < 4; ++r) {
          int m = m0 + wr * 64 + i * 16 + lq * 4 + r;
          int n = n0 + wc * 64 + j * 16 + lr;
          C[sl_idx8(m, n)] = f2bf(acc[i][j][r]);  // plain, lossless P
        }
  }
}

// ---------------- persistent recurrence kernel (parity-ring L2 flow) -------------
// 256 blocks: g = bid&7 (chain, rows g*8..+8, XCD g under default round-robin),
// jb = bid>>3 (j-cols jb*64..+64). 8 waves = kg(4, k-quarters 512) x jt(2). Wave: 16
// chunk loads (ring) + 32 MFMAs (16 vs LDS-W j-tile, 16 vs reg-W j-tile). Partials ->
// red LDS (dbuf); wave 0 reduces 4kg x 64j + P (from hseq, plain), relu, tags with
// parity, stores: hseq in place (phase 3), ring (plain -> L2), mirror (sc0sc1 -> LLC).
__global__ __launch_bounds__(512, 2) void rnn_recur(unsigned short* __restrict__ hseq,
                                                    unsigned short* __restrict__ ring,
                                                    unsigned short* __restrict__ mirror,
                                                    const float* __restrict__ Whh) {
  __shared__ u4 Wl[32 * 256];            // 128 KiB: [j_local 32][k-chunk 256], ^ (j&7)
  __shared__ float red[2][4][4][8][24];  // 24 KiB: [buf][kg][jtile 4][row 8][j 16 pad 24]
  const int tix = threadIdx.x;
  const int bid = (int)blockIdx.x;
  const int g = bid & 7;
  const int jb = bid >> 3;
  const int j0 = jb * 64;

  // one-time: W_hh j-rows j0..j0+32 -> swizzled LDS (f32 -> bf16)
  {
    const int jl = tix >> 4;
    const int ci = tix & 15;
#pragma unroll
    for (int q = 0; q < 16; ++q) {
      int cc = ci * 16 + q;
      const float* p = Whh + (size_t)(j0 + jl) * NH + cc * 8;
      float4 v0 = *(const float4*)p;
      float4 v1 = *(const float4*)(p + 4);
      float f[8] = {v0.x, v0.y, v0.z, v0.w, v1.x, v1.y, v1.z, v1.w};
      Wl[jl * 256 + (cc ^ (jl & 7))] = pack8(f);
    }
  }

  const int l = tix & 63, w = tix >> 6;
  const int lr = l & 15, lq = l >> 4;
  const int kg = w >> 1, jt = w & 1;

  // one-time: W_hh j-rows j0+32+jt*16+lr, k-quarter kg -> 16 reg frags
  bf8 wreg[16];
  {
    const float* p0 = Whh + (size_t)(j0 + 32 + jt * 16 + lr) * NH + kg * 512 + lq * 8;
#pragma unroll
    for (int kc = 0; kc < 16; ++kc) {
      const float* p = p0 + kc * 32;
      float4 v0 = *(const float4*)p;
      float4 v1 = *(const float4*)(p + 4);
      float f[8] = {v0.x, v0.y, v0.z, v0.w, v1.x, v1.y, v1.z, v1.w};
      wreg[kc] = __builtin_bit_cast(bf8, pack8(f));
    }
  }

  char* hb = (char*)hseq;
  char* rb = (char*)ring;
  char* mb = (char*)mirror;
  const u4 msk = {0x7fff7fffu, 0x7fff7fffu, 0x7fff7fffu, 0x7fff7fffu};

  // consumer lane constants
  const size_t rowoff = (size_t)(l & 7) * 128 + (size_t)lq * 16;
  // writer lane constants (wave 0): lane l -> row l>>3, j-octet (l&7)*8
  const size_t wboff = (size_t)(l >> 3) * 128 + (size_t)(l & 7) * 16;
  const int wtile = (l & 7) >> 1;
  const int wrow = l >> 3;
  const int wc0 = ((l & 7) & 1) * 8;

  u4 pre = {};  // P prefetch (writer wave only), plain bf16

  __syncthreads();  // Wl ready

  if (w == 0)  // P(0): plain load (phase-1 data, clean at kernel boundary)
    pre = *(const u4*)(hb + (((size_t)g) << 15) + ((size_t)jb << 10) + wboff);

  for (int ts = 0; ts < TT; ++ts) {
    f4 aL0 = {}, aL1 = {}, aR0 = {}, aR1 = {};

    if (ts > 0) {
      const unsigned expect = 1u - (((unsigned)(ts - 1) >> 2) & 1u);  // parity tag of h_{ts-1}
      const size_t xofs = ((size_t)(kg * 8) << 10) + rowoff;
      unsigned long long A0 =
          (unsigned long long)(uintptr_t)(rb + ((((size_t)((ts - 1) & 3)) * 8 + g) << 15) + xofs);
      unsigned long long A1 = A0 + 4096;
      unsigned long long M0 =
          (unsigned long long)(uintptr_t)(mb + ((((size_t)((ts - 1) & 3)) * 8 + g) << 15) + xofs);
      unsigned long long M1 = M0 + 4096;

      u4 av[16];
      int att = 0;
      for (;;) {
        if (att < 8) {
          // primary: ring via sc0 (bypass L1, served by the shared same-XCD L2)
          asm volatile(
              "global_load_dwordx4 %0, %16, off sc0\n\t"
              "global_load_dwordx4 %1, %16, off offset:64 sc0\n\t"
              "global_load_dwordx4 %2, %16, off offset:1024 sc0\n\t"
              "global_load_dwordx4 %3, %16, off offset:1088 sc0\n\t"
              "global_load_dwordx4 %4, %16, off offset:2048 sc0\n\t"
              "global_load_dwordx4 %5, %16, off offset:2112 sc0\n\t"
              "global_load_dwordx4 %6, %16, off offset:3072 sc0\n\t"
              "global_load_dwordx4 %7, %16, off offset:3136 sc0\n\t"
              "global_load_dwordx4 %8, %17, off sc0\n\t"
              "global_load_dwordx4 %9, %17, off offset:64 sc0\n\t"
              "global_load_dwordx4 %10, %17, off offset:1024 sc0\n\t"
              "global_load_dwordx4 %11, %17, off offset:1088 sc0\n\t"
              "global_load_dwordx4 %12, %17, off offset:2048 sc0\n\t"
              "global_load_dwordx4 %13, %17, off offset:2112 sc0\n\t"
              "global_load_dwordx4 %14, %17, off offset:3072 sc0\n\t"
              "global_load_dwordx4 %15, %17, off offset:3136 sc0\n\t"
              "s_waitcnt vmcnt(0)"
              : "=&v"(av[0]), "=&v"(av[1]), "=&v"(av[2]), "=&v"(av[3]),
                "=&v"(av[4]), "=&v"(av[5]), "=&v"(av[6]), "=&v"(av[7]),
                "=&v"(av[8]), "=&v"(av[9]), "=&v"(av[10]), "=&v"(av[11]),
                "=&v"(av[12]), "=&v"(av[13]), "=&v"(av[14]), "=&v"(av[15])
              : "v"(A0), "v"(A1)
              : "memory");
        } else {
          // fallback: LLC mirror (correct under any block->XCD placement)
          asm volatile(
              "global_load_dwordx4 %0, %16, off sc0 sc1\n\t"
              "global_load_dwordx4 %1, %16, off offset:64 sc0 sc1\n\t"
              "global_load_dwordx4 %2, %16, off offset:1024 sc0 sc1\n\t"
              "global_load_dwordx4 %3, %16, off offset:1088 sc0 sc1\n\t"
              "global_load_dwordx4 %4, %16, off offset:2048 sc0 sc1\n\t"
              "global_load_dwordx4 %5, %16, off offset:2112 sc0 sc1\n\t"
              "global_load_dwordx4 %6, %16, off offset:3072 sc0 sc1\n\t"
              "global_load_dwordx4 %7, %16, off offset:3136 sc0 sc1\n\t"
              "global_load_dwordx4 %8, %17, off sc0 sc1\n\t"
              "global_load_dwordx4 %9, %17, off offset:64 sc0 sc1\n\t"
              "global_load_dwordx4 %10, %17, off offset:1024 sc0 sc1\n\t"
              "global_load_dwordx4 %11, %17, off offset:1088 sc0 sc1\n\t"
              "global_load_dwordx4 %12, %17, off offset:2048 sc0 sc1\n\t"
              "global_load_dwordx4 %13, %17, off offset:2112 sc0 sc1\n\t"
              "global_load_dwordx4 %14, %17, off offset:3072 sc0 sc1\n\t"
              "global_load_dwordx4 %15, %17, off offset:3136 sc0 sc1\n\t"
              "s_waitcnt vmcnt(0)"
              : "=&v"(av[0]), "=&v"(av[1]), "=&v"(av[2]), "=&v"(av[3]),
                "=&v"(av[4]), "=&v"(av[5]), "=&v"(av[6]), "=&v"(av[7]),
                "=&v"(av[8]), "=&v"(av[9]), "=&v"(av[10]), "=&v"(av[11]),
                "=&v"(av[12]), "=&v"(av[13]), "=&v"(av[14]), "=&v"(av[15])
              : "v"(M0), "v"(M1)
              : "memory");
        }
        unsigned am = 0xffffffffu, om = 0u;
#pragma unroll
        for (int c = 0; c < 16; ++c)
#pragma unroll
          for (int d = 0; d < 4; ++d) {
            am &= av[c][d];
            om |= av[c][d];
          }
        bool ok = expect ? ((am & 0x80008000u) == 0x80008000u)
                         : ((om & 0x80008000u) == 0u);
        if (__ballot(ok) == ~0ull) break;
        ++att;
        __builtin_amdgcn_s_sleep(1);
        if (att > 65536) break;  // hang safety; never hit when logic is correct
      }

#pragma unroll
      for (int kc = 0; kc < 16; ++kc) {
        u4 v = av[kc] & msk;  // strip tag signs
        bf8 af = __builtin_bit_cast(bf8, v);
        int cc = kg * 64 + kc * 4 + lq;
        int rowL = jt * 16 + lr;
        bf8 bL = __builtin_bit_cast(bf8, Wl[rowL * 256 + (cc ^ (rowL & 7))]);
        if (kc & 1) {
          aL1 = __builtin_amdgcn_mfma_f32_16x16x32_bf16(af, bL, aL1, 0, 0, 0);
          aR1 = __builtin_amdgcn_mfma_f32_16x16x32_bf16(af, wreg[kc], aR1, 0, 0, 0);
        } else {
          aL0 = __builtin_amdgcn_mfma_f32_16x16x32_bf16(af, bL, aL0, 0, 0, 0);
          aR0 = __builtin_amdgcn_mfma_f32_16x16x32_bf16(af, wreg[kc], aR0, 0, 0, 0);
        }
      }
    }
    f4 aL = aL0 + aL1, aR = aR0 + aR1;

    const int buf = ts & 1;
    if (lq < 2) {  // real rows 0..7 only
#pragma unroll
      for (int i = 0; i < 4; ++i) {
        red[buf][kg][jt][lq * 4 + i][lr] = aL[i];
        red[buf][kg][2 + jt][lq * 4 + i][lr] = aR[i];
      }
    }
    __syncthreads();

    if (w == 0) {
      float pf[8];
#pragma unroll
      for (int e = 0; e < 8; ++e)
        pf[e] = bf2f((unsigned short)((pre[e >> 1] >> ((e & 1) * 16)) & 0xffffu));
      f4 s0 = {}, s1 = {};
      if (ts > 0) {
#pragma unroll
        for (int q = 0; q < 4; ++q) {
          s0 += *(const f4*)&red[buf][q][wtile][wrow][wc0];
          s1 += *(const f4*)&red[buf][q][wtile][wrow][wc0 + 4];
        }
      }
      float sf[8] = {s0[0], s0[1], s0[2], s0[3], s1[0], s1[1], s1[2], s1[3]};
      const unsigned tagm = (1u - (((unsigned)ts >> 2) & 1u)) ? 0x80008000u : 0u;
      u4 hv;
#pragma unroll
      for (int i = 0; i < 4; ++i) {
        float v0 = sf[2 * i] + pf[2 * i];
        float v1 = sf[2 * i + 1] + pf[2 * i + 1];
        v0 = v0 > 0.f ? v0 : 0.f;
        v1 = v1 > 0.f ? v1 : 0.f;
        hv[i] = ((unsigned)f2bf(v0) | ((unsigned)f2bf(v1) << 16)) | tagm;
      }
      const size_t sofs = ((size_t)jb << 10) + wboff;
      // persistent h for phase 3 (in place over consumed P_t; phase 3 strips tags)
      *(u4*)(hb + (((size_t)ts * 8 + g) << 15) + sofs) = hv;
      // ring: plain store -> dirty line in this XCD's L2 (visible to sc0 readers)
      *(u4*)(rb + ((((size_t)(ts & 3)) * 8 + g) << 15) + sofs) = hv;
      // mirror: write-through to LLC (placement-independent fallback)
      unsigned long long ma =
          (unsigned long long)(uintptr_t)(mb + ((((size_t)(ts & 3)) * 8 + g) << 15) + sofs);
      asm volatile("global_store_dwordx4 %0, %1, off sc0 sc1" ::"v"(ma), "v"(hv)
                   : "memory");
      // prefetch next P (own hseq slice; written only by this wave, at step ts+1)
      if (ts + 1 < TT)
        pre = *(const u4*)(hb + (((size_t)(ts + 1) * 8 + g) << 15) + sofs);
    }
  }
}

extern "C" void kernel_launch(void* const* d_in, const int* in_sizes, int n_in,
                              void* d_out, int out_size, void* d_ws, size_t ws_size,
                              hipStream_t stream) {
  const float* xs = (const float*)d_in[0];
  const float* Wih = (const float*)d_in[1];
  const float* Whh = (const float*)d_in[2];
  const float* Wout = (const float*)d_in[3];

  unsigned short* hseq = (unsigned short*)d_ws;  // [TT][8][32][8][64] bf16 = 128 MiB
  char* ringc = (char*)d_ws + (size_t)TT * BB * NH * 2;
  unsigned short* ring = (unsigned short*)ringc;               // 4-slot ring, 1 MiB
  unsigned short* mirror = (unsigned short*)(ringc + (4u << 18));  // 1 MiB

  // ring + mirror must start tag-invalid (signs clear) each call
  hipMemsetAsync(ringc, 0, (size_t)2 * (4u << 18), stream);

  // phase 1: P = xs @ W_ih^T -> plain bf16 sliced layout (lossless)
  gemm_bt<false, false><<<(TT * BB / 128) * (NH / 128), 256, 0, stream>>>(
      (const void*)xs, Wih, (void*)hseq, TT * BB, NH, NIN);

  // phase 2: recurrence (parity-ring L2 exchange, mirror fallback)
  rnn_recur<<<256, 512, 0, stream>>>(hseq, ring, mirror, Whh);

  // phase 3: out[b][t][o] = h_seq @ W_out^T (strips tags)
  gemm_bt<true, true><<<(TT * BB / 128) * (NOUT / 128), 256, 0, stream>>>(
      (const void*)hseq, Wout, d_out, TT * BB, NOUT, NH);
}

// Round 12
// 3835.420 us; speedup vs baseline: 4.2249x; 4.2249x over previous
//
#include <hip/hip_runtime.h>
#include <hip/hip_bf16.h>
#include <stdint.h>

// RNN: h_t = relu(xs_t @ W_ih^T + h_{t-1} @ W_hh^T); ys = (h_seq @ W_out^T) -> [B,T,O]
// R12 = R9 (best measured: 4 chains x 64 blocks, flag-flow, 16-deep bypass loads) + one
// change: the producer's vmcnt(0) drain between h-store and flag-store is DELETED.
// Safety: h is self-validating (all bf16 sign bits set; h>=0 so signs are free+lossless).
// Stale content of hseq[t] is phase-1's P, now stored as |P| (signs cleared) with the true
// sign bits in a separate 8 MiB sign-plane (1 bit/elem) that only the slice's own writer
// wave reads to reconstruct P exactly. Consumer: poll flag (hint) -> load data -> tag-check
// -> rare re-load. No drains, no fences on the critical path. Lossless everywhere.

#define TT 512
#define BB 64
#define NIN 1024
#define NH 2048
#define NOUT 1024

typedef __attribute__((ext_vector_type(8))) short bf8;
typedef __attribute__((ext_vector_type(4))) float f4;
typedef __attribute__((ext_vector_type(4))) unsigned int u4;

static __device__ __forceinline__ unsigned short f2bf(float f) {
  __hip_bfloat16 h = __float2bfloat16(f);
  return __builtin_bit_cast(unsigned short, h);
}
static __device__ __forceinline__ float bf2f(unsigned short v) {
  return __bfloat162float(__builtin_bit_cast(__hip_bfloat16, v));
}
static __device__ __forceinline__ u4 pack8(const float* f) {
  u4 r;
#pragma unroll
  for (int i = 0; i < 4; ++i) {
    unsigned lo = f2bf(f[2 * i]);
    unsigned hi = f2bf(f[2 * i + 1]);
    r[i] = lo | (hi << 16);
  }
  return r;
}

// sliced layout: (m = t*64+b, col) -> [t][g=b>>4][jb=col>>5][r=b&15][jl=col&31]
static __device__ __forceinline__ size_t sl_idx(int m, int col) {
  return ((((size_t)(m >> 6) * 4 + ((m & 63) >> 4)) * 64 + (col >> 5)) << 9) +
         (size_t)((m & 63) & 15) * 32 + (col & 31);
}

// ---------------- generic C[M,N] = A[M,K] * B[N,K]^T (bf16 MFMA) ----------------
// <false,false>: phase 1 — store |P| (signs cleared) + sign bits into plane (1b/elem).
// <true,true>:   phase 3 — A = tagged h (strip signs), store f32 out[b][t][n].
template <bool ABF, bool TRANS>
__global__ void gemm_bt(const void* __restrict__ Av, const float* __restrict__ Bw,
                        void* __restrict__ Cv, unsigned char* __restrict__ plane,
                        int M, int N, int K) {
  constexpr int BM = 128, BN = 128, BK = 32;
  __shared__ u4 As[BM * 4];
  __shared__ u4 Bs[BN * 4];
  const int nt = N / BN;
  const int mi = (int)blockIdx.x / nt;
  const int ni = (int)blockIdx.x % nt;
  const int m0 = mi * BM, n0 = ni * BN;
  const int t = threadIdx.x;
  const int l = t & 63, w = t >> 6, wr = w >> 1, wc = w & 1;
  const int lr = l & 15, lq = l >> 4;

  f4 acc[4][4] = {};

  const int srow = t >> 1;
  const int sc0 = (t & 1) * 2;
  const u4 msk = {0x7fff7fffu, 0x7fff7fffu, 0x7fff7fffu, 0x7fff7fffu};

  for (int kt = 0; kt < K; kt += BK) {
    if (ABF) {
      const unsigned short* A = (const unsigned short*)Av;
#pragma unroll
      for (int cc = 0; cc < 2; ++cc) {
        int c = sc0 + cc;
        u4 v = *(const u4*)(A + sl_idx(m0 + srow, kt + c * 8));
        v &= msk;  // strip h tag signs
        As[srow * 4 + (c ^ ((srow ^ (srow >> 2)) & 3))] = v;
      }
    } else {
      const float* A = (const float*)Av;
#pragma unroll
      for (int cc = 0; cc < 2; ++cc) {
        int c = sc0 + cc;
        const float* p = A + (size_t)(m0 + srow) * K + kt + c * 8;
        float4 v0 = *(const float4*)p;
        float4 v1 = *(const float4*)(p + 4);
        float f[8] = {v0.x, v0.y, v0.z, v0.w, v1.x, v1.y, v1.z, v1.w};
        As[srow * 4 + (c ^ ((srow ^ (srow >> 2)) & 3))] = pack8(f);
      }
    }
#pragma unroll
    for (int cc = 0; cc < 2; ++cc) {
      int c = sc0 + cc;
      const float* p = Bw + (size_t)(n0 + srow) * K + kt + c * 8;
      float4 v0 = *(const float4*)p;
      float4 v1 = *(const float4*)(p + 4);
      float f[8] = {v0.x, v0.y, v0.z, v0.w, v1.x, v1.y, v1.z, v1.w};
      Bs[srow * 4 + (c ^ ((srow ^ (srow >> 2)) & 3))] = pack8(f);
    }
    __syncthreads();

    bf8 a[4], b[4];
#pragma unroll
    for (int i = 0; i < 4; ++i) {
      int ra = wr * 64 + i * 16 + lr;
      a[i] = __builtin_bit_cast(bf8, As[ra * 4 + (lq ^ ((ra ^ (ra >> 2)) & 3))]);
      int rb = wc * 64 + i * 16 + lr;
      b[i] = __builtin_bit_cast(bf8, Bs[rb * 4 + (lq ^ ((rb ^ (rb >> 2)) & 3))]);
    }
#pragma unroll
    for (int i = 0; i < 4; ++i)
#pragma unroll
      for (int j = 0; j < 4; ++j)
        acc[i][j] = __builtin_amdgcn_mfma_f32_16x16x32_bf16(a[i], b[j], acc[i][j], 0, 0, 0);
    __syncthreads();
  }

  if (TRANS) {
    float* C = (float*)Cv;
#pragma unroll
    for (int i = 0; i < 4; ++i)
#pragma unroll
      for (int j = 0; j < 4; ++j)
#pragma unroll
        for (int r = 0; r < 4; ++r) {
          int m = m0 + wr * 64 + i * 16 + lq * 4 + r;
          int n = n0 + wc * 64 + j * 16 + lr;
          C[(size_t)(m & 63) * (TT * NOUT) + (size_t)(m >> 6) * NOUT + n] = acc[i][j][r];
        }
  } else {
    unsigned short* C = (unsigned short*)Cv;
#pragma unroll
    for (int i = 0; i < 4; ++i)
#pragma unroll
      for (int j = 0; j < 4; ++j)
#pragma unroll
        for (int r = 0; r < 4; ++r) {
          int m = m0 + wr * 64 + i * 16 + lq * 4 + r;
          int n = n0 + wc * 64 + j * 16 + lr;
          unsigned short v = f2bf(acc[i][j][r]);
          size_t sl = sl_idx(m, n);
          C[sl] = (unsigned short)(v & 0x7fffu);  // |P|: signs cleared = "not ready"
          unsigned long long bal = __ballot((v & 0x8000u) != 0);
          if ((l & 7) == 0)  // one lane per 8-elem granule writes the sign byte
            plane[sl >> 3] = (unsigned char)((bal >> (l & ~7)) & 0xffull);
        }
  }
}

// ---------------- persistent recurrence kernel (4 chains x 64 blocks) ------------
// block: g = (bid&7)>>1 (chain, rows g*16..+16), jb = (bid>>3)*2+(bid&1) (cols jb*32..+32).
// 8 waves = kg(4) x jh(2). Waves 0/1 are writers (jh=w). Producer: store tagged h
// (write-through) -> flag IMMEDIATELY (no drain). Consumer: poll flag -> 16-deep loads
// -> tag-check -> rare re-load.
__global__ __launch_bounds__(512, 2) void rnn_recur(unsigned short* __restrict__ hseq,
                                                    const unsigned char* __restrict__ plane,
                                                    const float* __restrict__ Whh,
                                                    unsigned* __restrict__ flags) {
  __shared__ u4 Wl[32 * 256];          // 128 KiB: [j_local 32][k-chunk 256], chunk ^ (j&7)
  __shared__ float red[2][4][16][36];  // 18 KiB: [buf][kg][row][j 32 pad 36]
  const int t = threadIdx.x;
  const int bid = (int)blockIdx.x;
  const int g = (bid & 7) >> 1;
  const int jb = ((bid >> 3) << 1) | (bid & 1);
  const int j0 = jb * 32;

  // one-time: W_hh j-slice (32 rows x 2048) -> swizzled LDS (f32 -> bf16)
  {
    const int jl = t >> 4;
    const int ci = t & 15;
#pragma unroll
    for (int q = 0; q < 16; ++q) {
      int cc = ci * 16 + q;
      const float* p = Whh + (size_t)(j0 + jl) * NH + cc * 8;
      float4 v0 = *(const float4*)p;
      float4 v1 = *(const float4*)(p + 4);
      float f[8] = {v0.x, v0.y, v0.z, v0.w, v1.x, v1.y, v1.z, v1.w};
      Wl[jl * 256 + (cc ^ (jl & 7))] = pack8(f);
    }
  }

  const int l = t & 63, w = t >> 6;
  const int lr = l & 15, lq = l >> 4;
  const int kg = w >> 1, jh = w & 1;

  char* hb = (char*)hseq;
  const size_t gofs = (size_t)g << 16;
  const u4 msk = {0x7fff7fffu, 0x7fff7fffu, 0x7fff7fffu, 0x7fff7fffu};

  // writer lane roles (waves 0/1, jh == w): 64 lanes = 16 rows x 4 j-quads (4 elems)
  const int wr_r = l >> 2;
  const int wjq = l & 3;
  const size_t wbyte = (size_t)wr_r * 64 + jh * 32 + wjq * 8;

  unsigned long long pre = 0;  // |P| for next step (4 bf16), writer waves only
  unsigned nib = 0;            // its 4 sign bits

  __syncthreads();  // Wl ready

  if (w < 2) {
    // h_0 = relu(P_0) from |P| + sign nibble; tagged write-through; flag=1 (NO drain)
    size_t e0 = gofs + ((size_t)jb << 10) + wbyte;
    unsigned long long p0 = __hip_atomic_load((const unsigned long long*)(hb + e0),
                                              __ATOMIC_RELAXED, __HIP_MEMORY_SCOPE_AGENT);
    unsigned nib0 = (plane[e0 >> 4] >> (((e0 >> 3) & 1) * 4)) & 0xfu;
    unsigned long long hv = 0x8000800080008000ull;  // tag all 4
#pragma unroll
    for (int i = 0; i < 4; ++i)
      if (!((nib0 >> i) & 1u)) hv |= ((p0 >> (16 * i)) & 0x7fffull) << (16 * i);
    __hip_atomic_store((unsigned long long*)(hb + e0), hv, __ATOMIC_RELAXED,
                       __HIP_MEMORY_SCOPE_AGENT);
    if (l == 0)
      __hip_atomic_store(flags + ((g * 64 + jb) * 2 + w), 1u, __ATOMIC_RELAXED,
                         __HIP_MEMORY_SCOPE_AGENT);
    size_t e1 = ((size_t)4 << 16) + gofs + ((size_t)jb << 10) + wbyte;
    pre = __hip_atomic_load((const unsigned long long*)(hb + e1), __ATOMIC_RELAXED,
                            __HIP_MEMORY_SCOPE_AGENT);
    nib = (plane[e1 >> 4] >> (((e1 >> 3) & 1) * 4)) & 0xfu;
  }

  for (int ts = 1; ts < TT; ++ts) {
    // poll the 32 producer-half flags covering this wave's k-quarter (hint only)
    {
      const unsigned* fp = flags + ((g * 64 + kg * 16 + (l >> 1)) * 2 + (l & 1));
      long spins = 0;
      for (;;) {
        unsigned fv = (l < 32) ? __hip_atomic_load(fp, __ATOMIC_RELAXED,
                                                   __HIP_MEMORY_SCOPE_AGENT)
                               : 0xffffffffu;
        if (__ballot(fv >= (unsigned)ts) == ~0ull) break;
        __builtin_amdgcn_s_sleep(1);
        if (++spins > (1L << 22)) break;  // hang safety
      }
    }
    asm volatile("" ::: "memory");  // keep data loads below the spin

    // 16 chunk loads (bypass), 16-deep; tag-validated, rare re-load
    const size_t rowoff = (size_t)(l & 15) * 64 + (size_t)(l >> 4) * 16;
    const size_t base =
        (((size_t)(ts - 1) * 4) << 16) + gofs + ((size_t)(kg * 16) << 10) + rowoff;
    unsigned long long a0 = (unsigned long long)(uintptr_t)(hb + base);
    unsigned long long a1 = a0 + 4096;
    unsigned long long a2 = a0 + 8192;
    unsigned long long a3 = a0 + 12288;
    u4 av[16];
    int att = 0;
    for (;;) {
      asm volatile(
          "global_load_dwordx4 %0, %16, off sc0 sc1\n\t"
          "global_load_dwordx4 %1, %16, off offset:1024 sc0 sc1\n\t"
          "global_load_dwordx4 %2, %16, off offset:2048 sc0 sc1\n\t"
          "global_load_dwordx4 %3, %16, off offset:3072 sc0 sc1\n\t"
          "global_load_dwordx4 %4, %17, off sc0 sc1\n\t"
          "global_load_dwordx4 %5, %17, off offset:1024 sc0 sc1\n\t"
          "global_load_dwordx4 %6, %17, off offset:2048 sc0 sc1\n\t"
          "global_load_dwordx4 %7, %17, off offset:3072 sc0 sc1\n\t"
          "global_load_dwordx4 %8, %18, off sc0 sc1\n\t"
          "global_load_dwordx4 %9, %18, off offset:1024 sc0 sc1\n\t"
          "global_load_dwordx4 %10, %18, off offset:2048 sc0 sc1\n\t"
          "global_load_dwordx4 %11, %18, off offset:3072 sc0 sc1\n\t"
          "global_load_dwordx4 %12, %19, off sc0 sc1\n\t"
          "global_load_dwordx4 %13, %19, off offset:1024 sc0 sc1\n\t"
          "global_load_dwordx4 %14, %19, off offset:2048 sc0 sc1\n\t"
          "global_load_dwordx4 %15, %19, off offset:3072 sc0 sc1\n\t"
          "s_waitcnt vmcnt(0)"
          : "=&v"(av[0]), "=&v"(av[1]), "=&v"(av[2]), "=&v"(av[3]),
            "=&v"(av[4]), "=&v"(av[5]), "=&v"(av[6]), "=&v"(av[7]),
            "=&v"(av[8]), "=&v"(av[9]), "=&v"(av[10]), "=&v"(av[11]),
            "=&v"(av[12]), "=&v"(av[13]), "=&v"(av[14]), "=&v"(av[15])
          : "v"(a0), "v"(a1), "v"(a2), "v"(a3)
          : "memory");
      unsigned am = 0xffffffffu;
#pragma unroll
      for (int c = 0; c < 16; ++c)
#pragma unroll
        for (int d = 0; d < 4; ++d) am &= av[c][d];
      bool ok = (am & 0x80008000u) == 0x80008000u;  // every granule tagged -> fresh h
      if (__ballot(ok) == ~0ull) break;
      __builtin_amdgcn_s_sleep(1);
      if (++att > (1 << 20)) break;  // hang safety; never hit when logic is correct
    }

    f4 acc0 = {}, acc1 = {};
#pragma unroll
    for (int c = 0; c < 16; ++c) {
      u4 v = av[c] & msk;  // strip tag signs
      bf8 af = __builtin_bit_cast(bf8, v);
      int ci = kg * 64 + c * 4 + lq;
      bf8 bfr = __builtin_bit_cast(bf8, Wl[(jh * 16 + lr) * 256 + (ci ^ (lr & 7))]);
      if (c & 1)
        acc1 = __builtin_amdgcn_mfma_f32_16x16x32_bf16(af, bfr, acc1, 0, 0, 0);
      else
        acc0 = __builtin_amdgcn_mfma_f32_16x16x32_bf16(af, bfr, acc0, 0, 0, 0);
    }
    f4 a2v = acc0 + acc1;

    const int buf = ts & 1;
#pragma unroll
    for (int i = 0; i < 4; ++i) red[buf][kg][(l >> 4) * 4 + i][jh * 16 + (l & 15)] = a2v[i];
    __syncthreads();

    if (w < 2) {
      __builtin_amdgcn_s_setprio(1);
      float pf[4];
#pragma unroll
      for (int i = 0; i < 4; ++i) {
        unsigned pv = (unsigned)((pre >> (16 * i)) & 0xffffull);
        pv |= ((nib >> i) & 1u) << 15;  // lossless sign restore
        pf[i] = bf2f((unsigned short)pv);
      }
      f4 s = {};
#pragma unroll
      for (int q = 0; q < 4; ++q) s += *(const f4*)&red[buf][q][wr_r][jh * 16 + wjq * 4];
      unsigned long long hv = 0;
#pragma unroll
      for (int i = 0; i < 4; ++i) {
        float v = s[i] + pf[i];
        v = v > 0.f ? v : 0.f;
        hv |= (unsigned long long)(unsigned short)(f2bf(v) | 0x8000u) << (16 * i);
      }
      size_t eo = (((size_t)ts * 4) << 16) + gofs + ((size_t)jb << 10) + wbyte;
      __hip_atomic_store((unsigned long long*)(hb + eo), hv, __ATOMIC_RELAXED,
                         __HIP_MEMORY_SCOPE_AGENT);
      // flag IMMEDIATELY -- no vmcnt drain; consumers validate data by tag
      if (l == 0)
        __hip_atomic_store(flags + ((g * 64 + jb) * 2 + w), (unsigned)(ts + 1),
                           __ATOMIC_RELAXED, __HIP_MEMORY_SCOPE_AGENT);
      if (ts + 1 < TT) {
        size_t en = (((size_t)(ts + 1) * 4) << 16) + gofs + ((size_t)jb << 10) + wbyte;
        pre = __hip_atomic_load((const unsigned long long*)(hb + en), __ATOMIC_RELAXED,
                                __HIP_MEMORY_SCOPE_AGENT);
        nib = (plane[en >> 4] >> (((en >> 3) & 1) * 4)) & 0xfu;
      }
      __builtin_amdgcn_s_setprio(0);
    }
  }
}

__global__ void kinit(unsigned* f) { f[threadIdx.x] = 0u; }

extern "C" void kernel_launch(void* const* d_in, const int* in_sizes, int n_in,
                              void* d_out, int out_size, void* d_ws, size_t ws_size,
                              hipStream_t stream) {
  const float* xs = (const float*)d_in[0];
  const float* Wih = (const float*)d_in[1];
  const float* Whh = (const float*)d_in[2];
  const float* Wout = (const float*)d_in[3];

  unsigned short* hseq = (unsigned short*)d_ws;  // [TT][4][64][16][32] bf16 = 128 MiB
  unsigned char* plane = (unsigned char*)d_ws + ((size_t)TT * BB * NH * 2);  // 8 MiB
  unsigned* flags = (unsigned*)(plane + ((size_t)TT * BB * NH / 8));         // 512 x u32

  kinit<<<1, 512, 0, stream>>>(flags);

  // phase 1: |P| = |xs @ W_ih^T| -> sliced layout; signs -> plane (lossless)
  gemm_bt<false, false><<<(TT * BB / 128) * (NH / 128), 256, 0, stream>>>(
      (const void*)xs, Wih, (void*)hseq, plane, TT * BB, NH, NIN);

  // phase 2: recurrence (flag hint + tag-validated data; no producer drain)
  rnn_recur<<<256, 512, 0, stream>>>(hseq, plane, Whh, flags);

  // phase 3: out[b][t][o] = h_seq @ W_out^T (strips tags)
  gemm_bt<true, true><<<(TT * BB / 128) * (NOUT / 128), 256, 0, stream>>>(
      (const void*)hseq, Wout, d_out, plane, TT * BB, NOUT, NH);
}